// Round 3
// baseline (362.047 us; speedup 1.0000x reference)
//
#include <hip/hip_runtime.h>
#include <stdint.h>

// ---------------------------------------------------------------------------
// SSM: q=1x1 reduce + L2norm; ss = clamp(unfold7x7 * center); 3x chained 3x3
// conv (+BN+relu) per pixel; 1x1 + BN; residual; FFN (1x1,relu,1x1).
// B=8, C=256, MID=64, H=W=64.  bf16 MFMA 16x16x32 for all heavy GEMMs.
// R3: encoder 1024 thr (4 waves/SIMD), du-sliced weight loads (VGPR<=128 so
//     weights/rows stay register-resident), HW packed bf16 cvt, MFMA k_qnorm.
// ---------------------------------------------------------------------------

typedef __attribute__((ext_vector_type(8))) __bf16 bf16x8;
typedef __attribute__((ext_vector_type(4))) float f32x4;

__device__ __forceinline__ ushort f2bf(float f) {
  uint32_t u = __builtin_bit_cast(uint32_t, f);
  u += 0x7fffu + ((u >> 16) & 1u);   // RNE
  return (ushort)(u >> 16);
}
__device__ __forceinline__ float bfu(ushort h) {
  return __builtin_bit_cast(float, ((uint32_t)h) << 16);
}
// pack two fp32 -> two bf16 (RNE); HW v_cvt_pk_bf16_f32 when available
__device__ __forceinline__ unsigned int pk2(float lo, float hi) {
#if __has_builtin(__builtin_amdgcn_cvt_pk_bf16_f32)
  auto r = __builtin_amdgcn_cvt_pk_bf16_f32(lo, hi);
  unsigned int u;
  __builtin_memcpy(&u, &r, 4);
  return u;
#else
  return (unsigned int)f2bf(lo) | ((unsigned int)f2bf(hi) << 16);
#endif
}
__device__ __forceinline__ f32x4 mfma16(bf16x8 a, bf16x8 b, f32x4 c) {
  return __builtin_amdgcn_mfma_f32_16x16x32_bf16(a, b, c, 0, 0, 0);
}

union BV8 { uint4 v; ushort u[8]; };

// ---------------------------------------------------------------------------
// Workspace layout (bytes)
// ---------------------------------------------------------------------------
#define OFF_WRB 0u          // w_red_b  bf16 [64][256]            32768
#define OFF_WCB 65536u      // wc_b     bf16 [3][9][64][64]       221184
#define OFF_SHC 286720u     // shift_c  fp32 [3][64]              768
#define OFF_WOB 287488u     // w_out_b  bf16 [256][64]            32768
#define OFF_SHO 320256u     // shift_o  fp32 [256]                1024
#define OFF_WF1 321280u     // w_f1_b   bf16 [256][256]           131072
#define OFF_WF2 452352u     // w_f2_b   bf16 [256][256]           131072
#define OFF_QN  583424u     // q_n      bf16 [32768][64]          4194304
#define OFF_Y   4777728u    // y        bf16 [32768][64]          4194304

// ---------------------------------------------------------------------------
// Kernel 0: weight prep (fold BN, cast to bf16)
// ---------------------------------------------------------------------------
__global__ __launch_bounds__(256) void k_prep(
    const float* __restrict__ w_red, const float* __restrict__ w_c, const float* __restrict__ b_c,
    const float* __restrict__ bn_g, const float* __restrict__ bn_b, const float* __restrict__ bn_m,
    const float* __restrict__ bn_v, const float* __restrict__ w_out, const float* __restrict__ b_out,
    const float* __restrict__ bno_g, const float* __restrict__ bno_b, const float* __restrict__ bno_m,
    const float* __restrict__ bno_v, const float* __restrict__ w_f1, const float* __restrict__ w_f2,
    ushort* __restrict__ w_red_b, ushort* __restrict__ wc_b, float* __restrict__ shift_c,
    ushort* __restrict__ w_out_b, float* __restrict__ shift_o,
    ushort* __restrict__ w_f1_b, ushort* __restrict__ w_f2_b)
{
  int i = blockIdx.x * 256 + threadIdx.x;
  if (i < 16384) {                       // w_red_b[m][c] (A-operand layout)
    w_red_b[i] = f2bf(w_red[i]);
    return;
  }
  i -= 16384;
  if (i < 110592) {                      // wc_b[s][tap][o][c] = w_c[s][o][c][du][dv] * bnscale
    int c = i & 63, o = (i >> 6) & 63, st = i >> 12;
    int tap = st % 9, s = st / 9;
    float sc = bn_g[s * 64 + o] * rsqrtf(bn_v[s * 64 + o] + 1e-5f);
    wc_b[i] = f2bf(w_c[((s * 64 + o) * 64 + c) * 9 + tap] * sc);
    return;
  }
  i -= 110592;
  if (i < 192) {                         // shift_c[s][o]
    int s = i >> 6, o = i & 63;
    float sc = bn_g[s * 64 + o] * rsqrtf(bn_v[s * 64 + o] + 1e-5f);
    shift_c[i] = (b_c[i] - bn_m[i]) * sc + bn_b[i];
    return;
  }
  i -= 192;
  if (i < 16384) {                       // w_out_b[o][c] (bno scale folded)
    int o = i >> 6;
    float sc = bno_g[o] * rsqrtf(bno_v[o] + 1e-5f);
    w_out_b[i] = f2bf(w_out[i] * sc);
    return;
  }
  i -= 16384;
  if (i < 256) {                         // shift_o[o]
    float sc = bno_g[i] * rsqrtf(bno_v[i] + 1e-5f);
    shift_o[i] = (b_out[i] - bno_m[i]) * sc + bno_b[i];
    return;
  }
  i -= 256;
  if (i < 65536) { w_f1_b[i] = f2bf(w_f1[i]); return; }
  i -= 65536;
  if (i < 65536) { w_f2_b[i] = f2bf(w_f2[i]); return; }
}

// ---------------------------------------------------------------------------
// Kernel 1: q = w_red @ x per pixel, L2-normalize -> q_n bf16.  MFMA version:
// stage x-tile transposed+bf16 in LDS, w_red as A-operand, shuffle-reduce norm.
// WG = 64 px, 4 waves (wave = 16 px, all 64 mids).
// ---------------------------------------------------------------------------
#define QN_STRIDE 264   // 256 + 8 pad (keeps 16B alignment)

__global__ __launch_bounds__(256) void k_qnorm(
    const float* __restrict__ x, const ushort* __restrict__ w_red_b, ushort* __restrict__ qn)
{
  __shared__ ushort xt[64 * QN_STRIDE];   // [px][c] bf16

  const int tid = threadIdx.x;
  const int pix0 = blockIdx.x * 64;
  const int b = pix0 >> 12, hw0 = pix0 & 4095;

  // stage: transpose [c][hw] fp32 -> [hw][c] bf16
  {
    const int cl = tid >> 2, hq = tid & 3;
    for (int cb = 0; cb < 4; ++cb) {
      const int c = cb * 64 + cl;
      const float* src = x + (size_t)(b * 256 + c) * 4096 + hw0 + hq * 16;
#pragma unroll
      for (int j = 0; j < 4; ++j) {
        float4 v = *(const float4*)(src + j * 4);
        const int hw = hq * 16 + j * 4;
        xt[(hw + 0) * QN_STRIDE + c] = f2bf(v.x);
        xt[(hw + 1) * QN_STRIDE + c] = f2bf(v.y);
        xt[(hw + 2) * QN_STRIDE + c] = f2bf(v.z);
        xt[(hw + 3) * QN_STRIDE + c] = f2bf(v.w);
      }
    }
  }
  __syncthreads();

  const int lane = tid & 63, w = tid >> 6;
  const int n = lane & 15, q = lane >> 4;
  const int px = w * 16 + n;
  const f32x4 zero = {0.f, 0.f, 0.f, 0.f};

  bf16x8 bfr[8];
#pragma unroll
  for (int kc = 0; kc < 8; ++kc)
    bfr[kc] = *(const bf16x8*)(xt + px * QN_STRIDE + kc * 32 + q * 8);

  f32x4 acc[4];
#pragma unroll
  for (int mt = 0; mt < 4; ++mt) {
    f32x4 a0 = zero, a1 = zero;
#pragma unroll
    for (int kc = 0; kc < 8; kc += 2) {
      a0 = mfma16(*(const bf16x8*)(w_red_b + (mt * 16 + n) * 256 + kc * 32 + q * 8), bfr[kc], a0);
      a1 = mfma16(*(const bf16x8*)(w_red_b + (mt * 16 + n) * 256 + (kc + 1) * 32 + q * 8), bfr[kc + 1], a1);
    }
    acc[mt] = a0 + a1;
  }

  float s = 0.f;
#pragma unroll
  for (int mt = 0; mt < 4; ++mt)
#pragma unroll
    for (int r = 0; r < 4; ++r) s += acc[mt][r] * acc[mt][r];
  s += __shfl_xor(s, 16, 64);
  s += __shfl_xor(s, 32, 64);
  const float inv = 1.0f / fmaxf(sqrtf(s), 1e-12f);

#pragma unroll
  for (int mt = 0; mt < 4; ++mt) {
    uint2 wv;
    wv.x = pk2(acc[mt][0] * inv, acc[mt][1] * inv);
    wv.y = pk2(acc[mt][2] * inv, acc[mt][3] * inv);
    *(uint2*)(qn + (size_t)(pix0 + px) * 64 + mt * 16 + q * 4) = wv;
  }
}

// ---------------------------------------------------------------------------
// Kernel 2: per-pixel encoder. WG = 16 pixels, 1024 thr = 16 waves
// (4 o-tiles x 4 position-groups).  du-sliced weight loads keep live VGPRs
// under 128 so weights + row frags are register-resident.
// ---------------------------------------------------------------------------
#define SS_BYTES (49 * 16 * 64 * 2)
#define O1_BYTES (25 * 16 * 64 * 2)
#define SMEM_ENC (SS_BYTES + O1_BYTES)   // 151552 bytes

__device__ __forceinline__ void store_act(ushort* buf, int pos, int n, int q, int o0,
                                          f32x4 acc, float4 sh) {
  uint2 wv;
  wv.x = pk2(fmaxf(acc[0] + sh.x, 0.0f), fmaxf(acc[1] + sh.y, 0.0f));
  wv.y = pk2(fmaxf(acc[2] + sh.z, 0.0f), fmaxf(acc[3] + sh.w, 0.0f));
  const int chunk = (o0 >> 3) + (q >> 1);
  *(uint2*)(buf + (pos * 16 + n) * 64 + ((chunk ^ (n & 7)) * 8) + (q & 1) * 4) = wv;
}

template<int NV, int IW, int OW>
__device__ __forceinline__ void conv_row(
    const ushort* __restrict__ inb, ushort* __restrict__ outb,
    const ushort* __restrict__ wst, const float4 sh,
    int u, int vlo, int o0, int n, int q, int rowoff, int c0, int c1)
{
  const f32x4 zero = {0.f, 0.f, 0.f, 0.f};
  f32x4 acc[NV];
#pragma unroll
  for (int v = 0; v < NV; ++v) acc[v] = zero;
#pragma unroll
  for (int du = 0; du < 3; ++du) {
    const ushort* rowb = inb + ((u + du) * IW + vlo) * 1024 + rowoff;
#pragma unroll
    for (int kc = 0; kc < 2; ++kc) {
      const int cc = kc ? c1 : c0;
      const int wofs = kc * 32 + q * 8;
      bf16x8 a[3];
#pragma unroll
      for (int dv = 0; dv < 3; ++dv)
        a[dv] = *(const bf16x8*)(wst + ((du * 3 + dv) * 64 + o0 + n) * 64 + wofs);
      bf16x8 rf[NV + 2];
#pragma unroll
      for (int j = 0; j < NV + 2; ++j)
        rf[j] = *(const bf16x8*)(rowb + j * 1024 + cc);
#pragma unroll
      for (int dv = 0; dv < 3; ++dv)
#pragma unroll
        for (int v = 0; v < NV; ++v)
          acc[v] = mfma16(a[dv], rf[v + dv], acc[v]);
    }
  }
#pragma unroll
  for (int v = 0; v < NV; ++v)
    store_act(outb, u * OW + vlo + v, n, q, o0, acc[v], sh);
}

__global__ __launch_bounds__(1024, 4) void k_encoder(
    const ushort* __restrict__ qn, const ushort* __restrict__ wc_b,
    const float* __restrict__ shift_c, ushort* __restrict__ yout)
{
  extern __shared__ char smem[];
  ushort* ss = (ushort*)smem;
  ushort* o1 = (ushort*)(smem + SS_BYTES);
  ushort* o2 = (ushort*)smem;          // reuses ss region (dead after conv1)

  const int tid = threadIdx.x;
  const int b = blockIdx.z;
  const int tr = blockIdx.y * 4;
  const int tc = blockIdx.x * 4;

  // ---- phase 0: build ss[uv][p][c] = relu(qn[nbr]*qn[center]), swizzled ----
  {
    const int p = tid & 15;
    const int g = tid >> 4;            // 0..63, one uv each (49 active)
    if (g < 49) {
      const int ph = tr + (p >> 2), pw = tc + (p & 3);
      const ushort* cen = qn + (size_t)((b << 12) + ph * 64 + pw) * 64;
      const int swp = p & 7;
      const int du = g / 7 - 3, dv = g % 7 - 3;
      const int nh = ph + du, nw = pw + dv;
      const bool ok = ((unsigned)nh < 64u) && ((unsigned)nw < 64u);
      const ushort* nb = qn + (size_t)((b << 12) + nh * 64 + nw) * 64;
      ushort* dst = ss + (g * 16 + p) * 64;
#pragma unroll
      for (int ch = 0; ch < 8; ++ch) {
        uint4 ov;
        if (ok) {
          BV8 cv; cv.v = *(const uint4*)(cen + ch * 8);
          BV8 nv; nv.v = *(const uint4*)(nb + ch * 8);
          float pr[8];
#pragma unroll
          for (int j = 0; j < 8; ++j)
            pr[j] = fmaxf(bfu(nv.u[j]) * bfu(cv.u[j]), 0.0f);
          ov.x = pk2(pr[0], pr[1]); ov.y = pk2(pr[2], pr[3]);
          ov.z = pk2(pr[4], pr[5]); ov.w = pk2(pr[6], pr[7]);
        } else {
          ov = make_uint4(0u, 0u, 0u, 0u);
        }
        *(uint4*)(dst + ((ch ^ swp) * 8)) = ov;
      }
    }
  }
  __syncthreads();

  const int lane = tid & 63, wvi = tid >> 6;   // 16 waves
  const int n = lane & 15, q = lane >> 4;
  const int ot = wvi & 3, grp = wvi >> 2;
  const int o0 = ot * 16;
  const int sw = n & 7;
  const int rowoff = n * 64;
  const int c0 = ((0 + q) ^ sw) * 8;
  const int c1 = ((4 + q) ^ sw) * 8;
  const f32x4 zero = {0.f, 0.f, 0.f, 0.f};

  // ---- conv1: 5x5 outputs over 7x7 ss (position-groups 7/6/6/6) ----
  {
    const float4 sh = *(const float4*)(shift_c + o0 + q * 4);
    const ushort* w1 = wc_b;
    if (grp == 0) {
      conv_row<5, 7, 5>(ss, o1, w1, sh, 0, 0, o0, n, q, rowoff, c0, c1);
      conv_row<2, 7, 5>(ss, o1, w1, sh, 1, 0, o0, n, q, rowoff, c0, c1);
    } else if (grp == 1) {
      conv_row<3, 7, 5>(ss, o1, w1, sh, 1, 2, o0, n, q, rowoff, c0, c1);
      conv_row<3, 7, 5>(ss, o1, w1, sh, 2, 0, o0, n, q, rowoff, c0, c1);
    } else if (grp == 2) {
      conv_row<2, 7, 5>(ss, o1, w1, sh, 2, 3, o0, n, q, rowoff, c0, c1);
      conv_row<4, 7, 5>(ss, o1, w1, sh, 3, 0, o0, n, q, rowoff, c0, c1);
    } else {
      conv_row<1, 7, 5>(ss, o1, w1, sh, 3, 4, o0, n, q, rowoff, c0, c1);
      conv_row<5, 7, 5>(ss, o1, w1, sh, 4, 0, o0, n, q, rowoff, c0, c1);
    }
  }
  __syncthreads();

  // ---- conv2: 3x3 outputs over 5x5 o1 (groups 3/2/2/2) ----
  {
    const float4 sh = *(const float4*)(shift_c + 64 + o0 + q * 4);
    const ushort* w2 = wc_b + 9 * 4096;
    if (grp == 0) {
      conv_row<3, 5, 3>(o1, o2, w2, sh, 0, 0, o0, n, q, rowoff, c0, c1);
    } else if (grp == 1) {
      conv_row<2, 5, 3>(o1, o2, w2, sh, 1, 0, o0, n, q, rowoff, c0, c1);
    } else if (grp == 2) {
      conv_row<1, 5, 3>(o1, o2, w2, sh, 1, 2, o0, n, q, rowoff, c0, c1);
      conv_row<1, 5, 3>(o1, o2, w2, sh, 2, 0, o0, n, q, rowoff, c0, c1);
    } else {
      conv_row<2, 5, 3>(o1, o2, w2, sh, 2, 1, o0, n, q, rowoff, c0, c1);
    }
  }
  __syncthreads();

  // ---- conv3: 1 output over 3x3 o2 -> y (global), grp 0 waves ----
  if (grp == 0) {
    const float4 sh = *(const float4*)(shift_c + 128 + o0 + q * 4);
    const ushort* w3 = wc_b + 18 * 4096;
    f32x4 a0 = zero, a1 = zero;
#pragma unroll
    for (int tap = 0; tap < 9; ++tap) {
      const ushort* rA = o2 + tap * 1024 + rowoff;
      a0 = mfma16(*(const bf16x8*)(w3 + (tap * 64 + o0 + n) * 64 + q * 8),
                  *(const bf16x8*)(rA + c0), a0);
      a1 = mfma16(*(const bf16x8*)(w3 + (tap * 64 + o0 + n) * 64 + 32 + q * 8),
                  *(const bf16x8*)(rA + c1), a1);
    }
    f32x4 acc = a0 + a1;
    uint2 wv2;
    wv2.x = pk2(fmaxf(acc[0] + sh.x, 0.0f), fmaxf(acc[1] + sh.y, 0.0f));
    wv2.y = pk2(fmaxf(acc[2] + sh.z, 0.0f), fmaxf(acc[3] + sh.w, 0.0f));
    const int ph = tr + (n >> 2), pw = tc + (n & 3);
    *(uint2*)(yout + (size_t)((b << 12) + ph * 64 + pw) * 64 + o0 + q * 4) = wv2;
  }
}

// ---------------------------------------------------------------------------
// Kernel 3: feat = BN(w_out@y); r = x + feat; out = w_f2@relu(w_f1@r+b1)+b2
// WG = 64 pixels (4 n-tiles); 4 waves split 256 output channels.
// ---------------------------------------------------------------------------
#define SMEM_OUT (2 * 64 * 256 * 2)   // rls + hls = 65536 bytes

__global__ __launch_bounds__(256) void k_out(
    const ushort* __restrict__ y, const float* __restrict__ x,
    const ushort* __restrict__ w_out_b, const float* __restrict__ shift_o,
    const ushort* __restrict__ w_f1_b, const float* __restrict__ b_f1,
    const ushort* __restrict__ w_f2_b, const float* __restrict__ b_f2,
    float* __restrict__ out)
{
  extern __shared__ char smem[];
  ushort* rls = (ushort*)smem;                    // [64 px][256 c] swizzled
  ushort* hls = (ushort*)(smem + 64 * 256 * 2);

  const int tid = threadIdx.x, lane = tid & 63, wv = tid >> 6;
  const int n = lane & 15, q = lane >> 4;
  const int pix0 = blockIdx.x * 64;
  const int b = pix0 >> 12, hw0 = pix0 & 4095;
  const int sw = n & 7;
  const f32x4 zero = {0.f, 0.f, 0.f, 0.f};

  // ---- stage A: feat + residual -> r (bf16, LDS, swizzled [px][c]) ----
  {
    bf16x8 wa[8];
#pragma unroll
    for (int mt = 0; mt < 4; ++mt) {
      const int ob = wv * 64 + mt * 16;
      wa[mt * 2]     = *(const bf16x8*)(w_out_b + (ob + n) * 64 + q * 8);
      wa[mt * 2 + 1] = *(const bf16x8*)(w_out_b + (ob + n) * 64 + 32 + q * 8);
    }
    for (int nt = 0; nt < 4; ++nt) {
      const int px0 = nt * 16;
      const bf16x8 yb0 = *(const bf16x8*)(y + (size_t)(pix0 + px0 + n) * 64 + q * 8);
      const bf16x8 yb1 = *(const bf16x8*)(y + (size_t)(pix0 + px0 + n) * 64 + 32 + q * 8);
#pragma unroll
      for (int mt = 0; mt < 4; ++mt) {
        const int ob = wv * 64 + mt * 16;
        f32x4 acc = zero;
        acc = mfma16(wa[mt * 2], yb0, acc);
        acc = mfma16(wa[mt * 2 + 1], yb1, acc);
        const float4 sh = *(const float4*)(shift_o + ob + q * 4);
        const float sha[4] = {sh.x, sh.y, sh.z, sh.w};
        float t[4];
#pragma unroll
        for (int r = 0; r < 4; ++r) {
          const int o = ob + q * 4 + r;
          const float xv = x[(size_t)(b * 256 + o) * 4096 + hw0 + px0 + n];
          t[r] = xv + acc[r] + sha[r];
        }
        uint2 v; v.x = pk2(t[0], t[1]); v.y = pk2(t[2], t[3]);
        const int chunk = (ob >> 3) + (q >> 1);
        *(uint2*)(rls + (px0 + n) * 256 + ((chunk ^ sw) * 8) + (q & 1) * 4) = v;
      }
    }
  }
  __syncthreads();

  // ---- stage B: h = relu(w_f1 @ r + b_f1) ----
  {
    bf16x8 wf[32];
#pragma unroll
    for (int mt = 0; mt < 4; ++mt)
#pragma unroll
      for (int kc = 0; kc < 8; ++kc)
        wf[mt * 8 + kc] = *(const bf16x8*)(w_f1_b + (size_t)(wv * 64 + mt * 16 + n) * 256 + kc * 32 + q * 8);
    for (int nt = 0; nt < 4; ++nt) {
      const int px0 = nt * 16;
      bf16x8 rb[8];
#pragma unroll
      for (int kc = 0; kc < 8; ++kc)
        rb[kc] = *(const bf16x8*)(rls + (px0 + n) * 256 + (((kc * 4 + q) ^ sw) * 8));
#pragma unroll
      for (int mt = 0; mt < 4; ++mt) {
        const int ob = wv * 64 + mt * 16;
        f32x4 a0 = zero, a1 = zero;
#pragma unroll
        for (int kc = 0; kc < 8; kc += 2) {
          a0 = mfma16(wf[mt * 8 + kc], rb[kc], a0);
          a1 = mfma16(wf[mt * 8 + kc + 1], rb[kc + 1], a1);
        }
        f32x4 acc = a0 + a1;
        const float4 bb = *(const float4*)(b_f1 + ob + q * 4);
        uint2 v;
        v.x = pk2(fmaxf(acc[0] + bb.x, 0.0f), fmaxf(acc[1] + bb.y, 0.0f));
        v.y = pk2(fmaxf(acc[2] + bb.z, 0.0f), fmaxf(acc[3] + bb.w, 0.0f));
        const int chunk = (ob >> 3) + (q >> 1);
        *(uint2*)(hls + (px0 + n) * 256 + ((chunk ^ sw) * 8) + (q & 1) * 4) = v;
      }
    }
  }
  __syncthreads();

  // ---- stage C: out = w_f2 @ h + b_f2 (fp32 store) ----
  {
    bf16x8 wf[32];
#pragma unroll
    for (int mt = 0; mt < 4; ++mt)
#pragma unroll
      for (int kc = 0; kc < 8; ++kc)
        wf[mt * 8 + kc] = *(const bf16x8*)(w_f2_b + (size_t)(wv * 64 + mt * 16 + n) * 256 + kc * 32 + q * 8);
    for (int nt = 0; nt < 4; ++nt) {
      const int px0 = nt * 16;
      bf16x8 rb[8];
#pragma unroll
      for (int kc = 0; kc < 8; ++kc)
        rb[kc] = *(const bf16x8*)(hls + (px0 + n) * 256 + (((kc * 4 + q) ^ sw) * 8));
#pragma unroll
      for (int mt = 0; mt < 4; ++mt) {
        const int ob = wv * 64 + mt * 16;
        f32x4 a0 = zero, a1 = zero;
#pragma unroll
        for (int kc = 0; kc < 8; kc += 2) {
          a0 = mfma16(wf[mt * 8 + kc], rb[kc], a0);
          a1 = mfma16(wf[mt * 8 + kc + 1], rb[kc + 1], a1);
        }
        f32x4 acc = a0 + a1;
        const float4 bb = *(const float4*)(b_f2 + ob + q * 4);
        const float bba[4] = {bb.x, bb.y, bb.z, bb.w};
#pragma unroll
        for (int r = 0; r < 4; ++r) {
          const int o = ob + q * 4 + r;
          out[(size_t)(b * 256 + o) * 4096 + hw0 + px0 + n] = acc[r] + bba[r];
        }
      }
    }
  }
}

// ---------------------------------------------------------------------------
extern "C" void kernel_launch(void* const* d_in, const int* in_sizes, int n_in,
                              void* d_out, int out_size, void* d_ws, size_t ws_size,
                              hipStream_t stream) {
  const float* x     = (const float*)d_in[0];
  const float* w_red = (const float*)d_in[1];
  const float* w_c   = (const float*)d_in[2];
  const float* b_c   = (const float*)d_in[3];
  const float* bn_g  = (const float*)d_in[4];
  const float* bn_b  = (const float*)d_in[5];
  const float* bn_m  = (const float*)d_in[6];
  const float* bn_v  = (const float*)d_in[7];
  const float* w_out = (const float*)d_in[8];
  const float* b_out = (const float*)d_in[9];
  const float* bno_g = (const float*)d_in[10];
  const float* bno_b = (const float*)d_in[11];
  const float* bno_m = (const float*)d_in[12];
  const float* bno_v = (const float*)d_in[13];
  const float* w_f1  = (const float*)d_in[14];
  const float* b_f1  = (const float*)d_in[15];
  const float* w_f2  = (const float*)d_in[16];
  const float* b_f2  = (const float*)d_in[17];

  char* ws = (char*)d_ws;
  ushort* w_red_b = (ushort*)(ws + OFF_WRB);
  ushort* wc_b    = (ushort*)(ws + OFF_WCB);
  float*  shift_c = (float*)(ws + OFF_SHC);
  ushort* w_out_b = (ushort*)(ws + OFF_WOB);
  float*  shift_o = (float*)(ws + OFF_SHO);
  ushort* w_f1_b  = (ushort*)(ws + OFF_WF1);
  ushort* w_f2_b  = (ushort*)(ws + OFF_WF2);
  ushort* qnb     = (ushort*)(ws + OFF_QN);
  ushort* yb      = (ushort*)(ws + OFF_Y);

  k_prep<<<1074, 256, 0, stream>>>(w_red, w_c, b_c, bn_g, bn_b, bn_m, bn_v,
                                   w_out, b_out, bno_g, bno_b, bno_m, bno_v,
                                   w_f1, w_f2,
                                   w_red_b, wc_b, shift_c, w_out_b, shift_o, w_f1_b, w_f2_b);
  k_qnorm<<<512, 256, 0, stream>>>(x, w_red_b, qnb);
  k_encoder<<<dim3(16, 16, 8), 1024, SMEM_ENC, stream>>>(qnb, wc_b, shift_c, yb);
  k_out<<<512, 256, SMEM_OUT, stream>>>(yb, x, w_out_b, shift_o, w_f1_b, b_f1, w_f2_b, b_f2,
                                        (float*)d_out);
}